// Round 2
// baseline (1406.050 us; speedup 1.0000x reference)
//
#include <hip/hip_runtime.h>
#include <hip/hip_bf16.h>

// Problem constants (match reference)
namespace {
constexpr int GH = 200, GW = 200, GD = 16;
constexpr int NV = GH * GW * GD;        // 640000 voxels
constexpr int NCLS = 18;                // output feature channels
constexpr int NF = 17;                  // per-gaussian feature channels (class 17 is zero)
constexpr int NG = 8192;
constexpr int KMAX = 10;                // static tile bound from reference
constexpr float VOX = 0.4f;
constexpr float LO0 = -40.f, LO1 = -40.f, LO2 = -1.f;
constexpr float HI0 = 40.f, HI1 = 40.f, HI2 = 5.4f;
constexpr float EPSV = 1e-6f;
}

// One wave (64 lanes) per gaussian. Per-gaussian setup computed redundantly by
// all lanes (broadcast loads, ~100 flops); lanes then stripe the tile voxels.
__global__ __launch_bounds__(256) void gv_splat(
    const float* __restrict__ means,   // [NG,3]
    const float* __restrict__ opac,    // [NG,1]
    const float* __restrict__ feats,   // [NG,17]
    const float* __restrict__ scales,  // [NG,3]
    const float* __restrict__ rots,    // [NG,4] wxyz
    float* __restrict__ gd,            // [NV]
    float* __restrict__ gf)            // [NV,17]
{
    const int g = (int)((blockIdx.x * blockDim.x + threadIdx.x) >> 6);
    const int lane = threadIdx.x & 63;
    if (g >= NG) return;

    const float mx = means[g * 3 + 0];
    const float my = means[g * 3 + 1];
    const float mz = means[g * 3 + 2];
    const float sx = scales[g * 3 + 0];
    const float sy = scales[g * 3 + 1];
    const float sz = scales[g * 3 + 2];
    float qw = rots[g * 4 + 0];
    float qx = rots[g * 4 + 1];
    float qy = rots[g * 4 + 2];
    float qz = rots[g * 4 + 3];
    const float op = opac[g];

    float fch[NF];
#pragma unroll
    for (int c = 0; c < NF; ++c) fch[c] = feats[g * NF + c];

    // normalized quaternion -> rotation matrix
    const float qn = rsqrtf(qw * qw + qx * qx + qy * qy + qz * qz);
    qw *= qn; qx *= qn; qy *= qn; qz *= qn;
    const float r00 = 1.f - 2.f * (qy * qy + qz * qz);
    const float r01 = 2.f * (qx * qy - qw * qz);
    const float r02 = 2.f * (qx * qz + qw * qy);
    const float r10 = 2.f * (qx * qy + qw * qz);
    const float r11 = 1.f - 2.f * (qx * qx + qz * qz);
    const float r12 = 2.f * (qy * qz - qw * qx);
    const float r20 = 2.f * (qx * qz - qw * qy);
    const float r21 = 2.f * (qy * qz + qw * qx);
    const float r22 = 1.f - 2.f * (qx * qx + qy * qy);

    const float s0 = sx * sx, s1 = sy * sy, s2 = sz * sz;
    // diag(cov) with cov = R diag(s^2) R^T
    const float c00 = r00 * r00 * s0 + r01 * r01 * s1 + r02 * r02 * s2;
    const float c11 = r10 * r10 * s0 + r11 * r11 * s1 + r12 * r12 * s2;
    const float c22 = r20 * r20 * s0 + r21 * r21 * s1 + r22 * r22 * s2;
    // cov_inv = R diag(1/s^2) R^T (analytic inverse, symmetric)
    const float i0 = 1.f / s0, i1 = 1.f / s1, i2 = 1.f / s2;
    const float a00 = r00 * r00 * i0 + r01 * r01 * i1 + r02 * r02 * i2;
    const float a01 = r00 * r10 * i0 + r01 * r11 * i1 + r02 * r12 * i2;
    const float a02 = r00 * r20 * i0 + r01 * r21 * i1 + r02 * r22 * i2;
    const float a11 = r10 * r10 * i0 + r11 * r11 * i1 + r12 * r12 * i2;
    const float a12 = r10 * r20 * i0 + r11 * r21 * i1 + r12 * r22 * i2;
    const float a22 = r20 * r20 * i0 + r21 * r21 * i1 + r22 * r22 * i2;

    const float m3[3] = { mx, my, mz };
    const float sg[3] = { sqrtf(c00), sqrtf(c11), sqrtf(c22) };
    const float lo3[3] = { LO0, LO1, LO2 };
    const float hi3[3] = { HI0, HI1, HI2 };
    const int dims[3] = { GH, GW, GD };

    int il[3], sp[3];
    bool valid = true;
#pragma unroll
    for (int ax = 0; ax < 3; ++ax) {
        const float bl = fminf(fmaxf(m3[ax] - 3.f * sg[ax], lo3[ax]), hi3[ax]);
        const float bh = fminf(fmaxf(m3[ax] + 3.f * sg[ax], lo3[ax]), hi3[ax]);
        valid = valid &&
                (((bl > lo3[ax]) || (bh > lo3[ax])) && ((bl < hi3[ax]) || (bh < hi3[ax])));
        const int a = (int)((bl - lo3[ax]) / VOX);  // >= 0 (bl clamped to lo)
        const int b = (int)((bh - lo3[ax]) / VOX);
        int s = b - a + 1;
        s = min(s, KMAX);             // reference's static K tile
        s = min(s, dims[ax] - a);     // vox < dims mask
        s = max(s, 0);
        il[ax] = a;
        sp[ax] = s;
    }
    if (!valid) return;

    const int syz = sp[1] * sp[2];
    const int total = sp[0] * syz;

    for (int t = lane; t < total; t += 64) {
        const int i = t / syz;
        const int r = t - i * syz;
        const int j = r / sp[2];
        const int k = r - j * sp[2];
        const int vx = il[0] + i;
        const int vy = il[1] + j;
        const int vz = il[2] + k;

        const float dx = ((float)vx + 0.5f) * VOX + LO0 - mx;
        const float dy = ((float)vy + 0.5f) * VOX + LO1 - my;
        const float dz = ((float)vz + 0.5f) * VOX + LO2 - mz;
        const float maha = a00 * dx * dx + a11 * dy * dy + a22 * dz * dz
                         + 2.f * (a01 * dx * dy + a02 * dx * dz + a12 * dy * dz);
        const float dens = op * __expf(-0.5f * maha);

        const int flat = (vx * GW + vy) * GD + vz;
        atomicAdd(gd + flat, dens);
        float* gp = gf + (size_t)flat * NF;
#pragma unroll
        for (int c = 0; c < NF; ++c) atomicAdd(gp + c, dens * fch[c]);
    }
}

// One thread per voxel: add the analytic "empty" gaussian, normalize, store f32.
__global__ __launch_bounds__(256) void gv_finalize(
    const float* __restrict__ gd,
    const float* __restrict__ gf,
    const float* __restrict__ empty_scalar,
    float* __restrict__ out)  // [NV] density, then [NV,18] feats
{
    const int v = blockIdx.x * blockDim.x + threadIdx.x;
    if (v >= NV) return;

    const int vx = v / (GW * GD);
    const int r = v - vx * (GW * GD);
    const int vy = r / GD;
    const int vz = r - vy * GD;

    const float cx = ((float)vx + 0.5f) * VOX + LO0;
    const float cy = ((float)vy + 0.5f) * VOX + LO1;
    const float cz = ((float)vz + 0.5f) * VOX + LO2;

    const float ex = (cx - 0.5f * (LO0 + HI0)) / (HI0 - LO0);
    const float ey = (cy - 0.5f * (LO1 + HI1)) / (HI1 - LO1);
    const float ez = (cz - 0.5f * (LO2 + HI2)) / (HI2 - LO2);
    const float dens_e = __expf(-0.5f * (ex * ex + ey * ey + ez * ez));

    const float density = gd[v] + dens_e;
    out[v] = density;

    const float inv = 1.f / fmaxf(density, EPSV);
    float* of = out + NV + (size_t)v * NCLS;
    const float* gp = gf + (size_t)v * NF;
#pragma unroll
    for (int c = 0; c < NF; ++c) of[c] = gp[c] * inv;
    const float es = empty_scalar[0];
    of[NF] = dens_e * es * inv;
}

extern "C" void kernel_launch(void* const* d_in, const int* in_sizes, int n_in,
                              void* d_out, int out_size, void* d_ws, size_t ws_size,
                              hipStream_t stream) {
    const float* means  = (const float*)d_in[0];
    const float* opac   = (const float*)d_in[1];
    const float* feats  = (const float*)d_in[2];
    const float* scales = (const float*)d_in[3];
    const float* rots   = (const float*)d_in[4];
    const float* esc    = (const float*)d_in[5];

    float* gd = (float*)d_ws;           // [NV] density accumulator
    float* gf = gd + NV;                // [NV,17] feature accumulator
    const size_t acc_bytes = (size_t)NV * (1 + NF) * sizeof(float);  // 46.1 MB

    hipMemsetAsync(d_ws, 0, acc_bytes, stream);  // ws is re-poisoned before every call

    gv_splat<<<NG / 4, 256, 0, stream>>>(means, opac, feats, scales, rots, gd, gf);
    gv_finalize<<<(NV + 255) / 256, 256, 0, stream>>>(gd, gf, esc, (float*)d_out);
}

// Round 3
// 139.135 us; speedup vs baseline: 10.1056x; 10.1056x over previous
//
#include <hip/hip_runtime.h>
#include <hip/hip_bf16.h>

// Problem constants (match reference)
namespace {
constexpr int GH = 200, GW = 200, GD = 16;
constexpr int NV = GH * GW * GD;        // 640000 voxels
constexpr int NCLS = 18;                // output feature channels
constexpr int NF = 17;                  // per-gaussian feature channels (class 17 is zero)
constexpr int NG = 8192;
constexpr int KMAX = 10;                // static tile bound from reference
constexpr float VOX = 0.4f;
constexpr float LO0 = -40.f, LO1 = -40.f, LO2 = -1.f;
constexpr float HI0 = 40.f, HI1 = 40.f, HI2 = 5.4f;
constexpr float EPSV = 1e-6f;

constexpr int TILE_XY = 4;              // tile = 4x4x16 voxels = 256 threads
constexpr int NTX = GH / TILE_XY;       // 50
constexpr int NTY = GW / TILE_XY;       // 50
constexpr int REC_DW = 32;              // padded record: 32 dwords = 128 B
constexpr int LIST_CAP = 1024;          // per-tile gaussian list capacity (avg ~16)
}

// ---------------------------------------------------------------------------
// Kernel A: one thread per gaussian. Precompute bbox (validity folded into
// sp=0) + evaluation record. Bbox math is bit-identical to the reference
// (literal /0.4f division, truncating int casts, clip = min(max)).
// Record layout (floats): [0..2]=mean, [3]=opacity,
// [4..9]=a00,a01,a02,a11,a12,a22 (cov_inv upper triangle), [10..26]=feats.
// ---------------------------------------------------------------------------
__global__ __launch_bounds__(256) void gv_pre(
    const float* __restrict__ means,   // [NG,3]
    const float* __restrict__ opac,    // [NG,1]
    const float* __restrict__ feats,   // [NG,17]
    const float* __restrict__ scales,  // [NG,3]
    const float* __restrict__ rots,    // [NG,4] wxyz
    int4* __restrict__ boxes,          // [NG] {il0, il1, il2, sp0|sp1<<8|sp2<<16}
    float* __restrict__ recs)          // [NG * REC_DW]
{
    const int g = blockIdx.x * blockDim.x + threadIdx.x;
    if (g >= NG) return;

    const float mx = means[g * 3 + 0];
    const float my = means[g * 3 + 1];
    const float mz = means[g * 3 + 2];
    const float sx = scales[g * 3 + 0];
    const float sy = scales[g * 3 + 1];
    const float sz = scales[g * 3 + 2];
    float qw = rots[g * 4 + 0];
    float qx = rots[g * 4 + 1];
    float qy = rots[g * 4 + 2];
    float qz = rots[g * 4 + 3];

    // normalized quaternion -> rotation matrix
    const float qn = rsqrtf(qw * qw + qx * qx + qy * qy + qz * qz);
    qw *= qn; qx *= qn; qy *= qn; qz *= qn;
    const float r00 = 1.f - 2.f * (qy * qy + qz * qz);
    const float r01 = 2.f * (qx * qy - qw * qz);
    const float r02 = 2.f * (qx * qz + qw * qy);
    const float r10 = 2.f * (qx * qy + qw * qz);
    const float r11 = 1.f - 2.f * (qx * qx + qz * qz);
    const float r12 = 2.f * (qy * qz - qw * qx);
    const float r20 = 2.f * (qx * qz - qw * qy);
    const float r21 = 2.f * (qy * qz + qw * qx);
    const float r22 = 1.f - 2.f * (qx * qx + qy * qy);

    const float s0 = sx * sx, s1 = sy * sy, s2 = sz * sz;
    const float c00 = r00 * r00 * s0 + r01 * r01 * s1 + r02 * r02 * s2;
    const float c11 = r10 * r10 * s0 + r11 * r11 * s1 + r12 * r12 * s2;
    const float c22 = r20 * r20 * s0 + r21 * r21 * s1 + r22 * r22 * s2;
    const float i0 = 1.f / s0, i1 = 1.f / s1, i2 = 1.f / s2;
    const float a00 = r00 * r00 * i0 + r01 * r01 * i1 + r02 * r02 * i2;
    const float a01 = r00 * r10 * i0 + r01 * r11 * i1 + r02 * r12 * i2;
    const float a02 = r00 * r20 * i0 + r01 * r21 * i1 + r02 * r22 * i2;
    const float a11 = r10 * r10 * i0 + r11 * r11 * i1 + r12 * r12 * i2;
    const float a12 = r10 * r20 * i0 + r11 * r21 * i1 + r12 * r22 * i2;
    const float a22 = r20 * r20 * i0 + r21 * r21 * i1 + r22 * r22 * i2;

    const float m3[3] = { mx, my, mz };
    const float sg[3] = { sqrtf(c00), sqrtf(c11), sqrtf(c22) };
    const float lo3[3] = { LO0, LO1, LO2 };
    const float hi3[3] = { HI0, HI1, HI2 };
    const int dims[3] = { GH, GW, GD };

    int il[3], sp[3];
    bool valid = true;
#pragma unroll
    for (int ax = 0; ax < 3; ++ax) {
        const float bl = fminf(fmaxf(m3[ax] - 3.f * sg[ax], lo3[ax]), hi3[ax]);
        const float bh = fminf(fmaxf(m3[ax] + 3.f * sg[ax], lo3[ax]), hi3[ax]);
        valid = valid &&
                (((bl > lo3[ax]) || (bh > lo3[ax])) && ((bl < hi3[ax]) || (bh < hi3[ax])));
        const int a = (int)((bl - lo3[ax]) / VOX);
        const int b = (int)((bh - lo3[ax]) / VOX);
        int s = b - a + 1;
        s = min(s, KMAX);             // reference's static K tile
        s = min(s, dims[ax] - a);     // vox < dims mask
        s = max(s, 0);
        il[ax] = a;
        sp[ax] = s;
    }

    int pack = valid ? (sp[0] | (sp[1] << 8) | (sp[2] << 16)) : 0;
    boxes[g] = make_int4(il[0], il[1], il[2], pack);

    float* R = recs + (size_t)g * REC_DW;
    R[0] = mx; R[1] = my; R[2] = mz; R[3] = opac[g];
    R[4] = a00; R[5] = a01; R[6] = a02; R[7] = a11; R[8] = a12; R[9] = a22;
#pragma unroll
    for (int c = 0; c < NF; ++c) R[10 + c] = feats[g * NF + c];
}

// ---------------------------------------------------------------------------
// Kernel B: one block per 4x4x16 voxel tile, one thread per voxel.
// Phase 1: brute-force bbox overlap vs all NG boxes, compact survivors to LDS.
// Phase 2: evaluate list, accumulate 18 channels in registers.
// Epilogue: fused empty-gaussian + normalization + output store.
// ---------------------------------------------------------------------------
__global__ __launch_bounds__(256) void gv_gather(
    const int4* __restrict__ boxes,
    const float* __restrict__ recs,
    const float* __restrict__ empty_scalar,
    float* __restrict__ out)           // [NV] density, then [NV,18] feats
{
    __shared__ int s_list[LIST_CAP];
    __shared__ int s_cnt;

    const int t = threadIdx.x;
    if (t == 0) s_cnt = 0;
    __syncthreads();

    const int tx = blockIdx.x / NTY;
    const int ty = blockIdx.x - tx * NTY;
    const int X0 = tx * TILE_XY;
    const int Y0 = ty * TILE_XY;

    // Phase 1: overlap test (tile z-range covers all of [0,GD))
    for (int g = t; g < NG; g += 256) {
        const int4 b = boxes[g];
        const int sp0 = b.w & 255;
        const int sp1 = (b.w >> 8) & 255;
        const int sp2 = (b.w >> 16) & 255;
        const bool ov = (sp0 > 0) & (sp1 > 0) & (sp2 > 0) &
                        (b.x < X0 + TILE_XY) & (b.x + sp0 > X0) &
                        (b.y < Y0 + TILE_XY) & (b.y + sp1 > Y0);
        if (ov) {
            const int idx = atomicAdd(&s_cnt, 1);
            if (idx < LIST_CAP) s_list[idx] = g;
        }
    }
    __syncthreads();
    const int n = min(s_cnt, LIST_CAP);

    // This thread's voxel
    const int lz = t & 15;
    const int ly = (t >> 4) & 3;
    const int lx = t >> 6;
    const int vx = X0 + lx;
    const int vy = Y0 + ly;
    const int vz = lz;
    const float cx = ((float)vx + 0.5f) * VOX + LO0;
    const float cy = ((float)vy + 0.5f) * VOX + LO1;
    const float cz = ((float)vz + 0.5f) * VOX + LO2;

    float accd = 0.f;
    float accf[NF];
#pragma unroll
    for (int c = 0; c < NF; ++c) accf[c] = 0.f;

    // Phase 2: evaluate the tile's gaussian list
    for (int i = 0; i < n; ++i) {
        const int g = __builtin_amdgcn_readfirstlane(s_list[i]);
        const int4 b = boxes[g];
        const float* R = recs + (size_t)g * REC_DW;

        const bool in =
            ((unsigned)(vx - b.x) < (unsigned)(b.w & 255)) &
            ((unsigned)(vy - b.y) < (unsigned)((b.w >> 8) & 255)) &
            ((unsigned)(vz - b.z) < (unsigned)((b.w >> 16) & 255));

        const float dx = cx - R[0];
        const float dy = cy - R[1];
        const float dz = cz - R[2];
        const float maha = R[4] * dx * dx + R[7] * dy * dy + R[9] * dz * dz
                         + 2.f * (R[5] * dx * dy + R[6] * dx * dz + R[8] * dy * dz);
        const float dens = R[3] * __expf(-0.5f * maha);

        if (in) {
            accd += dens;
#pragma unroll
            for (int c = 0; c < NF; ++c) accf[c] += dens * R[10 + c];
        }
    }

    // Epilogue: empty gaussian + normalize + store
    const float ex = (cx - 0.5f * (LO0 + HI0)) / (HI0 - LO0);
    const float ey = (cy - 0.5f * (LO1 + HI1)) / (HI1 - LO1);
    const float ez = (cz - 0.5f * (LO2 + HI2)) / (HI2 - LO2);
    const float dens_e = __expf(-0.5f * (ex * ex + ey * ey + ez * ez));

    const float density = accd + dens_e;
    const int v = (vx * GW + vy) * GD + vz;
    out[v] = density;

    const float inv = 1.f / fmaxf(density, EPSV);
    float* of = out + NV + (size_t)v * NCLS;
#pragma unroll
    for (int c = 0; c < NF; ++c) of[c] = accf[c] * inv;
    of[NF] = dens_e * empty_scalar[0] * inv;
}

extern "C" void kernel_launch(void* const* d_in, const int* in_sizes, int n_in,
                              void* d_out, int out_size, void* d_ws, size_t ws_size,
                              hipStream_t stream) {
    const float* means  = (const float*)d_in[0];
    const float* opac   = (const float*)d_in[1];
    const float* feats  = (const float*)d_in[2];
    const float* scales = (const float*)d_in[3];
    const float* rots   = (const float*)d_in[4];
    const float* esc    = (const float*)d_in[5];

    int4*  boxes = (int4*)d_ws;                       // 8192 * 16 B = 128 KB
    float* recs  = (float*)((char*)d_ws + (size_t)NG * sizeof(int4));  // 1 MB

    gv_pre<<<NG / 256, 256, 0, stream>>>(means, opac, feats, scales, rots, boxes, recs);
    gv_gather<<<NTX * NTY, 256, 0, stream>>>(boxes, recs, esc, (float*)d_out);
}

// Round 4
// 113.066 us; speedup vs baseline: 12.4357x; 1.2306x over previous
//
#include <hip/hip_runtime.h>

// Problem constants (match reference)
namespace {
constexpr int GH = 200, GW = 200, GD = 16;
constexpr int NV = GH * GW * GD;        // 640000 voxels
constexpr int NCLS = 18;                // output feature channels
constexpr int NF = 17;                  // per-gaussian feature channels (class 17 is zero)
constexpr int NG = 8192;
constexpr int KMAX = 10;                // static tile bound from reference
constexpr float VOX = 0.4f;
constexpr float LO0 = -40.f, LO1 = -40.f, LO2 = -1.f;
constexpr float HI0 = 40.f, HI1 = 40.f, HI2 = 5.4f;
constexpr float EPSV = 1e-6f;

constexpr int TILE_XY = 4;              // tile = 4x4x16 voxels = 256 threads
constexpr int NTX = GH / TILE_XY;       // 50
constexpr int NTY = GW / TILE_XY;       // 50
constexpr int NT = NTX * NTY;           // 2500 tiles
constexpr int REC_DW = 32;              // padded record: 32 dwords = 128 B
constexpr int CAP = 1024;               // per-tile list capacity (avg ~17, P(>1024)~0)
}

// ---------------------------------------------------------------------------
// Kernel A: one thread per gaussian. Compute bbox + eval record (bit-identical
// bbox math to the reference: literal /0.4f, truncating casts, clip=min(max)),
// then scatter the gaussian index into every overlapped tile's list.
// Record layout (floats): [0..2]=mean, [3]=opacity,
// [4..9]=a00,a01,a02,a11,a12,a22 (cov_inv upper triangle), [10..26]=feats.
// ---------------------------------------------------------------------------
__global__ __launch_bounds__(256) void gv_bin(
    const float* __restrict__ means,   // [NG,3]
    const float* __restrict__ opac,    // [NG,1]
    const float* __restrict__ feats,   // [NG,17]
    const float* __restrict__ scales,  // [NG,3]
    const float* __restrict__ rots,    // [NG,4] wxyz
    int4* __restrict__ boxes,          // [NG] {il0, il1, il2, sp0|sp1<<8|sp2<<16}
    float* __restrict__ recs,          // [NG * REC_DW]
    int* __restrict__ counts,          // [NT], pre-zeroed
    int* __restrict__ lists)           // [NT * CAP]
{
    const int g = blockIdx.x * blockDim.x + threadIdx.x;
    if (g >= NG) return;

    const float mx = means[g * 3 + 0];
    const float my = means[g * 3 + 1];
    const float mz = means[g * 3 + 2];
    const float sx = scales[g * 3 + 0];
    const float sy = scales[g * 3 + 1];
    const float sz = scales[g * 3 + 2];
    float qw = rots[g * 4 + 0];
    float qx = rots[g * 4 + 1];
    float qy = rots[g * 4 + 2];
    float qz = rots[g * 4 + 3];

    // normalized quaternion -> rotation matrix
    const float qn = rsqrtf(qw * qw + qx * qx + qy * qy + qz * qz);
    qw *= qn; qx *= qn; qy *= qn; qz *= qn;
    const float r00 = 1.f - 2.f * (qy * qy + qz * qz);
    const float r01 = 2.f * (qx * qy - qw * qz);
    const float r02 = 2.f * (qx * qz + qw * qy);
    const float r10 = 2.f * (qx * qy + qw * qz);
    const float r11 = 1.f - 2.f * (qx * qx + qz * qz);
    const float r12 = 2.f * (qy * qz - qw * qx);
    const float r20 = 2.f * (qx * qz - qw * qy);
    const float r21 = 2.f * (qy * qz + qw * qx);
    const float r22 = 1.f - 2.f * (qx * qx + qy * qy);

    const float s0 = sx * sx, s1 = sy * sy, s2 = sz * sz;
    const float c00 = r00 * r00 * s0 + r01 * r01 * s1 + r02 * r02 * s2;
    const float c11 = r10 * r10 * s0 + r11 * r11 * s1 + r12 * r12 * s2;
    const float c22 = r20 * r20 * s0 + r21 * r21 * s1 + r22 * r22 * s2;
    const float i0 = 1.f / s0, i1 = 1.f / s1, i2 = 1.f / s2;
    const float a00 = r00 * r00 * i0 + r01 * r01 * i1 + r02 * r02 * i2;
    const float a01 = r00 * r10 * i0 + r01 * r11 * i1 + r02 * r12 * i2;
    const float a02 = r00 * r20 * i0 + r01 * r21 * i1 + r02 * r22 * i2;
    const float a11 = r10 * r10 * i0 + r11 * r11 * i1 + r12 * r12 * i2;
    const float a12 = r10 * r20 * i0 + r11 * r21 * i1 + r12 * r22 * i2;
    const float a22 = r20 * r20 * i0 + r21 * r21 * i1 + r22 * r22 * i2;

    const float m3[3] = { mx, my, mz };
    const float sg[3] = { sqrtf(c00), sqrtf(c11), sqrtf(c22) };
    const float lo3[3] = { LO0, LO1, LO2 };
    const float hi3[3] = { HI0, HI1, HI2 };
    const int dims[3] = { GH, GW, GD };

    int il[3], sp[3];
    bool valid = true;
#pragma unroll
    for (int ax = 0; ax < 3; ++ax) {
        const float bl = fminf(fmaxf(m3[ax] - 3.f * sg[ax], lo3[ax]), hi3[ax]);
        const float bh = fminf(fmaxf(m3[ax] + 3.f * sg[ax], lo3[ax]), hi3[ax]);
        valid = valid &&
                (((bl > lo3[ax]) || (bh > lo3[ax])) && ((bl < hi3[ax]) || (bh < hi3[ax])));
        const int a = (int)((bl - lo3[ax]) / VOX);
        const int b = (int)((bh - lo3[ax]) / VOX);
        int s = b - a + 1;
        s = min(s, KMAX);             // reference's static K tile
        s = min(s, dims[ax] - a);     // vox < dims mask
        s = max(s, 0);
        il[ax] = a;
        sp[ax] = s;
    }

    boxes[g] = make_int4(il[0], il[1], il[2], sp[0] | (sp[1] << 8) | (sp[2] << 16));

    float* R = recs + (size_t)g * REC_DW;
    R[0] = mx; R[1] = my; R[2] = mz; R[3] = opac[g];
    R[4] = a00; R[5] = a01; R[6] = a02; R[7] = a11; R[8] = a12; R[9] = a22;
#pragma unroll
    for (int c = 0; c < NF; ++c) R[10 + c] = feats[g * NF + c];

    if (!valid || sp[0] <= 0 || sp[1] <= 0 || sp[2] <= 0) return;

    // scatter into overlapped tiles (<= 4x4 tiles since bbox span <= 10 voxels)
    const int tx0 = il[0] / TILE_XY;
    const int tx1 = (il[0] + sp[0] - 1) / TILE_XY;
    const int ty0 = il[1] / TILE_XY;
    const int ty1 = (il[1] + sp[1] - 1) / TILE_XY;
    for (int tx = tx0; tx <= tx1; ++tx)
        for (int ty = ty0; ty <= ty1; ++ty) {
            const int tile = tx * NTY + ty;
            const int idx = atomicAdd(counts + tile, 1);
            if (idx < CAP) lists[(size_t)tile * CAP + idx] = g;
        }
}

// ---------------------------------------------------------------------------
// Kernel B: one block per 4x4x16 voxel tile, one thread per voxel.
// Reads the precomputed per-tile list; software-pipelined entry loop
// (prefetch next g + box + 10-float record while computing current).
// Epilogue: fused empty-gaussian + normalization + output store.
// ---------------------------------------------------------------------------
__global__ __launch_bounds__(256) void gv_gather(
    const int4* __restrict__ boxes,
    const float* __restrict__ recs,
    const int* __restrict__ counts,
    const int* __restrict__ lists,
    const float* __restrict__ empty_scalar,
    float* __restrict__ out)           // [NV] density, then [NV,18] feats
{
    const int tile = blockIdx.x;
    const int tx = tile / NTY;
    const int ty = tile - tx * NTY;
    const int X0 = tx * TILE_XY;
    const int Y0 = ty * TILE_XY;

    const int t = threadIdx.x;
    const int lz = t & 15;
    const int ly = (t >> 4) & 3;
    const int lx = t >> 6;
    const int vx = X0 + lx;
    const int vy = Y0 + ly;
    const int vz = lz;
    const float cx = ((float)vx + 0.5f) * VOX + LO0;
    const float cy = ((float)vy + 0.5f) * VOX + LO1;
    const float cz = ((float)vz + 0.5f) * VOX + LO2;

    const int n = min(counts[tile], CAP);
    const int* __restrict__ lst = lists + (size_t)tile * CAP;

    float accd = 0.f;
    float accf[NF];
#pragma unroll
    for (int c = 0; c < NF; ++c) accf[c] = 0.f;

    // pipeline stage: next entry's index, box, and 10-dword eval record
    int g1 = 0;
    int4 b1 = make_int4(0, 0, 0, 0);
    float p1[10];
#pragma unroll
    for (int u = 0; u < 10; ++u) p1[u] = 0.f;
    if (n > 0) {
        g1 = __builtin_amdgcn_readfirstlane(lst[0]);
        b1 = boxes[g1];
        const float* R = recs + (size_t)g1 * REC_DW;
#pragma unroll
        for (int u = 0; u < 10; ++u) p1[u] = R[u];
    }

    for (int i = 0; i < n; ++i) {
        const int g0 = g1;
        const int4 b0 = b1;
        float p0[10];
#pragma unroll
        for (int u = 0; u < 10; ++u) p0[u] = p1[u];
        // feature loads: address known at iteration entry -> issue early
        const float* __restrict__ F0 = recs + (size_t)g0 * REC_DW + 10;
        float f0[NF];
#pragma unroll
        for (int c = 0; c < NF; ++c) f0[c] = F0[c];

        if (i + 1 < n) {
            g1 = __builtin_amdgcn_readfirstlane(lst[i + 1]);
            b1 = boxes[g1];
            const float* R = recs + (size_t)g1 * REC_DW;
#pragma unroll
            for (int u = 0; u < 10; ++u) p1[u] = R[u];
        }

        const bool in =
            ((unsigned)(vx - b0.x) < (unsigned)(b0.w & 255)) &
            ((unsigned)(vy - b0.y) < (unsigned)((b0.w >> 8) & 255)) &
            ((unsigned)(vz - b0.z) < (unsigned)((b0.w >> 16) & 255));

        const float dx = cx - p0[0];
        const float dy = cy - p0[1];
        const float dz = cz - p0[2];
        const float maha = p0[4] * dx * dx + p0[7] * dy * dy + p0[9] * dz * dz
                         + 2.f * (p0[5] * dx * dy + p0[6] * dx * dz + p0[8] * dy * dz);
        const float dens = p0[3] * __expf(-0.5f * maha);

        if (in) {
            accd += dens;
#pragma unroll
            for (int c = 0; c < NF; ++c) accf[c] += dens * f0[c];
        }
    }

    // Epilogue: empty gaussian + normalize + store
    const float ex = (cx - 0.5f * (LO0 + HI0)) / (HI0 - LO0);
    const float ey = (cy - 0.5f * (LO1 + HI1)) / (HI1 - LO1);
    const float ez = (cz - 0.5f * (LO2 + HI2)) / (HI2 - LO2);
    const float dens_e = __expf(-0.5f * (ex * ex + ey * ey + ez * ez));

    const float density = accd + dens_e;
    const int v = (vx * GW + vy) * GD + vz;
    out[v] = density;

    const float inv = 1.f / fmaxf(density, EPSV);
    float* of = out + NV + (size_t)v * NCLS;
#pragma unroll
    for (int c = 0; c < NF; ++c) of[c] = accf[c] * inv;
    of[NF] = dens_e * empty_scalar[0] * inv;
}

extern "C" void kernel_launch(void* const* d_in, const int* in_sizes, int n_in,
                              void* d_out, int out_size, void* d_ws, size_t ws_size,
                              hipStream_t stream) {
    const float* means  = (const float*)d_in[0];
    const float* opac   = (const float*)d_in[1];
    const float* feats  = (const float*)d_in[2];
    const float* scales = (const float*)d_in[3];
    const float* rots   = (const float*)d_in[4];
    const float* esc    = (const float*)d_in[5];

    // workspace layout (all 128B-aligned): boxes | recs | counts | lists
    int4*  boxes  = (int4*)d_ws;                              // 128 KB
    float* recs   = (float*)(boxes + NG);                     // 1 MB
    int*   counts = (int*)(recs + (size_t)NG * REC_DW);       // 10 KB
    int*   lists  = counts + ((NT + 63) & ~63);               // 10.2 MB

    hipMemsetAsync(counts, 0, sizeof(int) * ((NT + 63) & ~63), stream);

    gv_bin<<<NG / 256, 256, 0, stream>>>(means, opac, feats, scales, rots,
                                         boxes, recs, counts, lists);
    gv_gather<<<NT, 256, 0, stream>>>(boxes, recs, counts, lists, esc, (float*)d_out);
}

// Round 5
// 108.254 us; speedup vs baseline: 12.9884x; 1.0444x over previous
//
#include <hip/hip_runtime.h>

// Problem constants (match reference)
namespace {
constexpr int GH = 200, GW = 200, GD = 16;
constexpr int NV = GH * GW * GD;        // 640000 voxels
constexpr int NCLS = 18;                // output feature channels
constexpr int NF = 17;                  // per-gaussian feature channels (class 17 is zero)
constexpr int NG = 8192;
constexpr int KMAX = 10;                // static tile bound from reference
constexpr float VOX = 0.4f;
constexpr float LO0 = -40.f, LO1 = -40.f, LO2 = -1.f;
constexpr float HI0 = 40.f, HI1 = 40.f, HI2 = 5.4f;
constexpr float EPSV = 1e-6f;

constexpr int TILE_XY = 4;              // tile = 4x4x16 voxels, one wave per tile
constexpr int NTX = GH / TILE_XY;       // 50
constexpr int NTY = GW / TILE_XY;       // 50
constexpr int NT = NTX * NTY;           // 2500 tiles
constexpr int REC_DW = 32;              // padded record: 32 dwords = 128 B
constexpr int CAP = 1024;               // per-tile list capacity (avg ~19)
}

// ---------------------------------------------------------------------------
// Kernel A: one thread per gaussian. Compute bbox + eval record (bit-identical
// bbox math to the reference: literal /0.4f, truncating casts, clip=min(max)),
// then scatter the gaussian index into every overlapped tile's list.
// Record layout (floats): [0..2]=mean, [3]=opacity,
// [4..9]=a00,a01,a02,a11,a12,a22 (cov_inv upper triangle), [10..26]=feats.
// ---------------------------------------------------------------------------
__global__ __launch_bounds__(256) void gv_bin(
    const float* __restrict__ means,   // [NG,3]
    const float* __restrict__ opac,    // [NG,1]
    const float* __restrict__ feats,   // [NG,17]
    const float* __restrict__ scales,  // [NG,3]
    const float* __restrict__ rots,    // [NG,4] wxyz
    int4* __restrict__ boxes,          // [NG] {il0, il1, il2, sp0|sp1<<8|sp2<<16}
    float* __restrict__ recs,          // [NG * REC_DW]
    int* __restrict__ counts,          // [NT], pre-zeroed
    int* __restrict__ lists)           // [NT * CAP]
{
    const int g = blockIdx.x * blockDim.x + threadIdx.x;
    if (g >= NG) return;

    const float mx = means[g * 3 + 0];
    const float my = means[g * 3 + 1];
    const float mz = means[g * 3 + 2];
    const float sx = scales[g * 3 + 0];
    const float sy = scales[g * 3 + 1];
    const float sz = scales[g * 3 + 2];
    float qw = rots[g * 4 + 0];
    float qx = rots[g * 4 + 1];
    float qy = rots[g * 4 + 2];
    float qz = rots[g * 4 + 3];

    // normalized quaternion -> rotation matrix
    const float qn = rsqrtf(qw * qw + qx * qx + qy * qy + qz * qz);
    qw *= qn; qx *= qn; qy *= qn; qz *= qn;
    const float r00 = 1.f - 2.f * (qy * qy + qz * qz);
    const float r01 = 2.f * (qx * qy - qw * qz);
    const float r02 = 2.f * (qx * qz + qw * qy);
    const float r10 = 2.f * (qx * qy + qw * qz);
    const float r11 = 1.f - 2.f * (qx * qx + qz * qz);
    const float r12 = 2.f * (qy * qz - qw * qx);
    const float r20 = 2.f * (qx * qz - qw * qy);
    const float r21 = 2.f * (qy * qz + qw * qx);
    const float r22 = 1.f - 2.f * (qx * qx + qy * qy);

    const float s0 = sx * sx, s1 = sy * sy, s2 = sz * sz;
    const float c00 = r00 * r00 * s0 + r01 * r01 * s1 + r02 * r02 * s2;
    const float c11 = r10 * r10 * s0 + r11 * r11 * s1 + r12 * r12 * s2;
    const float c22 = r20 * r20 * s0 + r21 * r21 * s1 + r22 * r22 * s2;
    const float i0 = 1.f / s0, i1 = 1.f / s1, i2 = 1.f / s2;
    const float a00 = r00 * r00 * i0 + r01 * r01 * i1 + r02 * r02 * i2;
    const float a01 = r00 * r10 * i0 + r01 * r11 * i1 + r02 * r12 * i2;
    const float a02 = r00 * r20 * i0 + r01 * r21 * i1 + r02 * r22 * i2;
    const float a11 = r10 * r10 * i0 + r11 * r11 * i1 + r12 * r12 * i2;
    const float a12 = r10 * r20 * i0 + r11 * r21 * i1 + r12 * r22 * i2;
    const float a22 = r20 * r20 * i0 + r21 * r21 * i1 + r22 * r22 * i2;

    const float m3[3] = { mx, my, mz };
    const float sg[3] = { sqrtf(c00), sqrtf(c11), sqrtf(c22) };
    const float lo3[3] = { LO0, LO1, LO2 };
    const float hi3[3] = { HI0, HI1, HI2 };
    const int dims[3] = { GH, GW, GD };

    int il[3], sp[3];
    bool valid = true;
#pragma unroll
    for (int ax = 0; ax < 3; ++ax) {
        const float bl = fminf(fmaxf(m3[ax] - 3.f * sg[ax], lo3[ax]), hi3[ax]);
        const float bh = fminf(fmaxf(m3[ax] + 3.f * sg[ax], lo3[ax]), hi3[ax]);
        valid = valid &&
                (((bl > lo3[ax]) || (bh > lo3[ax])) && ((bl < hi3[ax]) || (bh < hi3[ax])));
        const int a = (int)((bl - lo3[ax]) / VOX);
        const int b = (int)((bh - lo3[ax]) / VOX);
        int s = b - a + 1;
        s = min(s, KMAX);             // reference's static K tile
        s = min(s, dims[ax] - a);     // vox < dims mask
        s = max(s, 0);
        il[ax] = a;
        sp[ax] = s;
    }

    boxes[g] = make_int4(il[0], il[1], il[2], sp[0] | (sp[1] << 8) | (sp[2] << 16));

    float* R = recs + (size_t)g * REC_DW;
    R[0] = mx; R[1] = my; R[2] = mz; R[3] = opac[g];
    R[4] = a00; R[5] = a01; R[6] = a02; R[7] = a11; R[8] = a12; R[9] = a22;
#pragma unroll
    for (int c = 0; c < NF; ++c) R[10 + c] = feats[g * NF + c];

    if (!valid || sp[0] <= 0 || sp[1] <= 0 || sp[2] <= 0) return;

    // scatter into overlapped tiles (<= 4x4 tiles since bbox span <= 10 voxels)
    const int tx0 = il[0] / TILE_XY;
    const int tx1 = (il[0] + sp[0] - 1) / TILE_XY;
    const int ty0 = il[1] / TILE_XY;
    const int ty1 = (il[1] + sp[1] - 1) / TILE_XY;
    for (int tx = tx0; tx <= tx1; ++tx)
        for (int ty = ty0; ty <= ty1; ++ty) {
            const int tile = tx * NTY + ty;
            const int idx = atomicAdd(counts + tile, 1);
            if (idx < CAP) lists[(size_t)tile * CAP + idx] = g;
        }
}

// ---------------------------------------------------------------------------
// Kernel B: ONE WAVE per 4x4x16 tile; each lane owns 4 voxels along z
// (lane = lx<<4 | ly<<2 | zq, voxels vz = 4*zq .. 4*zq+3).
// Per entry: 27-dword record loaded once per wave (uniform -> scalar loads),
// full-record prefetch one entry ahead; maha factored per-lane as
// q0 + dz*(q1 + a22*dz); 4 independent accumulation chains per lane.
// Epilogue: fused empty-gaussian + normalize; float4 density store,
// 9x float2 feature stores per voxel.
// ---------------------------------------------------------------------------
__global__ __launch_bounds__(64) void gv_gather(
    const int4* __restrict__ boxes,
    const float* __restrict__ recs,
    const int* __restrict__ counts,
    const int* __restrict__ lists,
    const float* __restrict__ empty_scalar,
    float* __restrict__ out)           // [NV] density, then [NV,18] feats
{
    const int tile = blockIdx.x;
    const int tx = tile / NTY;
    const int ty = tile - tx * NTY;

    const int lane = threadIdx.x;      // 0..63
    const int lx = lane >> 4;
    const int ly = (lane >> 2) & 3;
    const int vz0 = (lane & 3) << 2;   // z-group base: 0,4,8,12

    const int vx = tx * TILE_XY + lx;
    const int vy = ty * TILE_XY + ly;
    const float cx = ((float)vx + 0.5f) * VOX + LO0;
    const float cy = ((float)vy + 0.5f) * VOX + LO1;

    const int n = min(counts[tile], CAP);
    const int* __restrict__ lst = lists + (size_t)tile * CAP;

    float accd[4] = { 0.f, 0.f, 0.f, 0.f };
    float accf[4][NF];
#pragma unroll
    for (int j = 0; j < 4; ++j)
#pragma unroll
        for (int c = 0; c < NF; ++c) accf[j][c] = 0.f;

    // prefetch pipeline: next entry's box + full 27-dword record (wave-uniform)
    int4 b1 = make_int4(0, 0, 0, 0);
    float P1[27];
#pragma unroll
    for (int u = 0; u < 27; ++u) P1[u] = 0.f;
    if (n > 0) {
        const int g = __builtin_amdgcn_readfirstlane(lst[0]);
        b1 = boxes[g];
        const float* R = recs + (size_t)g * REC_DW;
#pragma unroll
        for (int u = 0; u < 27; ++u) P1[u] = R[u];
    }

    for (int i = 0; i < n; ++i) {
        const int4 b0 = b1;
        float P0[27];
#pragma unroll
        for (int u = 0; u < 27; ++u) P0[u] = P1[u];

        if (i + 1 < n) {
            const int g = __builtin_amdgcn_readfirstlane(lst[i + 1]);
            b1 = boxes[g];
            const float* R = recs + (size_t)g * REC_DW;
#pragma unroll
            for (int u = 0; u < 27; ++u) P1[u] = R[u];
        }

        const bool inxy =
            ((unsigned)(vx - b0.x) < (unsigned)(b0.w & 255)) &
            ((unsigned)(vy - b0.y) < (unsigned)((b0.w >> 8) & 255));
        const unsigned spz = (unsigned)((b0.w >> 16) & 255);

        const float dx = cx - P0[0];
        const float dy = cy - P0[1];
        // maha(dz) = q0 + dz*(q1 + a22*dz); exactly the same terms as the
        // reference's quadratic form, re-associated (fp-benign).
        const float q0 = P0[4] * dx * dx + P0[7] * dy * dy + 2.f * P0[5] * dx * dy;
        const float q1 = 2.f * (P0[6] * dx + P0[8] * dy);

#pragma unroll
        for (int j = 0; j < 4; ++j) {
            const float cz = ((float)(vz0 + j) + 0.5f) * VOX + LO2;
            const float dz = cz - P0[2];
            const float maha = q0 + dz * (q1 + P0[9] * dz);
            const bool in = inxy & ((unsigned)(vz0 + j - b0.z) < spz);
            const float dens = P0[3] * __expf(-0.5f * maha);
            if (in) {
                accd[j] += dens;
#pragma unroll
                for (int c = 0; c < NF; ++c) accf[j][c] += dens * P0[10 + c];
            }
        }
    }

    // Epilogue: empty gaussian + normalize + store
    const float es = empty_scalar[0];
    const float ex = (cx - 0.5f * (LO0 + HI0)) / (HI0 - LO0);
    const float ey = (cy - 0.5f * (LO1 + HI1)) / (HI1 - LO1);
    const float exy = ex * ex + ey * ey;

    float dsv[4], dev[4];
#pragma unroll
    for (int j = 0; j < 4; ++j) {
        const float cz = ((float)(vz0 + j) + 0.5f) * VOX + LO2;
        const float ez = (cz - 0.5f * (LO2 + HI2)) / (HI2 - LO2);
        dev[j] = __expf(-0.5f * (exy + ez * ez));
        dsv[j] = accd[j] + dev[j];
    }

    const int vbase = (vx * GW + vy) * GD + vz0;     // multiple of 4
    *(float4*)(out + vbase) = make_float4(dsv[0], dsv[1], dsv[2], dsv[3]);

#pragma unroll
    for (int j = 0; j < 4; ++j) {
        const float inv = 1.f / fmaxf(dsv[j], EPSV);
        float vals[NCLS];
#pragma unroll
        for (int c = 0; c < NF; ++c) vals[c] = accf[j][c] * inv;
        vals[NF] = dev[j] * es * inv;
        float2* of2 = (float2*)(out + NV + (size_t)(vbase + j) * NCLS);  // 8B aligned
#pragma unroll
        for (int p = 0; p < NCLS / 2; ++p)
            of2[p] = make_float2(vals[2 * p], vals[2 * p + 1]);
    }
}

extern "C" void kernel_launch(void* const* d_in, const int* in_sizes, int n_in,
                              void* d_out, int out_size, void* d_ws, size_t ws_size,
                              hipStream_t stream) {
    const float* means  = (const float*)d_in[0];
    const float* opac   = (const float*)d_in[1];
    const float* feats  = (const float*)d_in[2];
    const float* scales = (const float*)d_in[3];
    const float* rots   = (const float*)d_in[4];
    const float* esc    = (const float*)d_in[5];

    // workspace layout (all 128B-aligned): boxes | recs | counts | lists
    int4*  boxes  = (int4*)d_ws;                              // 128 KB
    float* recs   = (float*)(boxes + NG);                     // 1 MB
    int*   counts = (int*)(recs + (size_t)NG * REC_DW);       // 10 KB
    int*   lists  = counts + ((NT + 63) & ~63);               // 10.2 MB

    hipMemsetAsync(counts, 0, sizeof(int) * ((NT + 63) & ~63), stream);

    gv_bin<<<NG / 256, 256, 0, stream>>>(means, opac, feats, scales, rots,
                                         boxes, recs, counts, lists);
    gv_gather<<<NT, 64, 0, stream>>>(boxes, recs, counts, lists, esc, (float*)d_out);
}

// Round 6
// 105.383 us; speedup vs baseline: 13.3423x; 1.0272x over previous
//
#include <hip/hip_runtime.h>

// Problem constants (match reference)
namespace {
constexpr int GH = 200, GW = 200, GD = 16;
constexpr int NV = GH * GW * GD;        // 640000 voxels
constexpr int NCLS = 18;                // output feature channels
constexpr int NF = 17;                  // per-gaussian feature channels (class 17 is zero)
constexpr int NG = 8192;
constexpr int KMAX = 10;                // static tile bound from reference
constexpr float VOX = 0.4f;
constexpr float LO0 = -40.f, LO1 = -40.f, LO2 = -1.f;
constexpr float HI0 = 40.f, HI1 = 40.f, HI2 = 5.4f;
constexpr float EPSV = 1e-6f;

constexpr int TILE_XY = 4;              // tile = 4x4x16 voxels, one wave per tile
constexpr int NTX = GH / TILE_XY;       // 50
constexpr int NTY = GW / TILE_XY;       // 50
constexpr int NT = NTX * NTY;           // 2500 tiles
constexpr int REC_DW = 32;              // record: 32 dwords = 128 B (incl. box)
constexpr int REC_V4 = REC_DW / 4;      // 8 float4
constexpr int CAP = 1024;               // per-tile list capacity (avg ~15)
constexpr int CH = 32;                  // entries staged per LDS chunk

constexpr float NHL2E = -0.72134752044448170368f;  // -0.5 * log2(e)
}

// ---------------------------------------------------------------------------
// Kernel A: one thread per gaussian. Bbox math is bit-identical to the
// reference (literal /0.4f, truncating casts, clip=min(max)). Writes one
// 128 B record per gaussian and scatters its index into overlapped tile lists.
// Record (floats): [0..2]=mean, [3]=opacity,
// [4]=s*a00 [5]=s*a11 [6]=s*a22 [7]=2s*a01 [8]=2s*a02 [9]=2s*a12  (s=-0.5*log2e)
// [10..26]=feats, [27..29]=il0..il2 (int bits), [30]=sp pack (int bits), [31]=0
// ---------------------------------------------------------------------------
__global__ __launch_bounds__(256) void gv_bin(
    const float* __restrict__ means,   // [NG,3]
    const float* __restrict__ opac,    // [NG,1]
    const float* __restrict__ feats,   // [NG,17]
    const float* __restrict__ scales,  // [NG,3]
    const float* __restrict__ rots,    // [NG,4] wxyz
    float* __restrict__ recs,          // [NG * REC_DW]
    int* __restrict__ counts,          // [NT], pre-zeroed
    int* __restrict__ lists)           // [NT * CAP]
{
    const int g = blockIdx.x * blockDim.x + threadIdx.x;
    if (g >= NG) return;

    const float mx = means[g * 3 + 0];
    const float my = means[g * 3 + 1];
    const float mz = means[g * 3 + 2];
    const float sx = scales[g * 3 + 0];
    const float sy = scales[g * 3 + 1];
    const float sz = scales[g * 3 + 2];
    float qw = rots[g * 4 + 0];
    float qx = rots[g * 4 + 1];
    float qy = rots[g * 4 + 2];
    float qz = rots[g * 4 + 3];

    // normalized quaternion -> rotation matrix
    const float qn = rsqrtf(qw * qw + qx * qx + qy * qy + qz * qz);
    qw *= qn; qx *= qn; qy *= qn; qz *= qn;
    const float r00 = 1.f - 2.f * (qy * qy + qz * qz);
    const float r01 = 2.f * (qx * qy - qw * qz);
    const float r02 = 2.f * (qx * qz + qw * qy);
    const float r10 = 2.f * (qx * qy + qw * qz);
    const float r11 = 1.f - 2.f * (qx * qx + qz * qz);
    const float r12 = 2.f * (qy * qz - qw * qx);
    const float r20 = 2.f * (qx * qz - qw * qy);
    const float r21 = 2.f * (qy * qz + qw * qx);
    const float r22 = 1.f - 2.f * (qx * qx + qy * qy);

    const float s0 = sx * sx, s1 = sy * sy, s2 = sz * sz;
    const float c00 = r00 * r00 * s0 + r01 * r01 * s1 + r02 * r02 * s2;
    const float c11 = r10 * r10 * s0 + r11 * r11 * s1 + r12 * r12 * s2;
    const float c22 = r20 * r20 * s0 + r21 * r21 * s1 + r22 * r22 * s2;
    const float i0 = 1.f / s0, i1 = 1.f / s1, i2 = 1.f / s2;
    const float a00 = r00 * r00 * i0 + r01 * r01 * i1 + r02 * r02 * i2;
    const float a01 = r00 * r10 * i0 + r01 * r11 * i1 + r02 * r12 * i2;
    const float a02 = r00 * r20 * i0 + r01 * r21 * i1 + r02 * r22 * i2;
    const float a11 = r10 * r10 * i0 + r11 * r11 * i1 + r12 * r12 * i2;
    const float a12 = r10 * r20 * i0 + r11 * r21 * i1 + r12 * r22 * i2;
    const float a22 = r20 * r20 * i0 + r21 * r21 * i1 + r22 * r22 * i2;

    const float m3[3] = { mx, my, mz };
    const float sg[3] = { sqrtf(c00), sqrtf(c11), sqrtf(c22) };
    const float lo3[3] = { LO0, LO1, LO2 };
    const float hi3[3] = { HI0, HI1, HI2 };
    const int dims[3] = { GH, GW, GD };

    int il[3], sp[3];
    bool valid = true;
#pragma unroll
    for (int ax = 0; ax < 3; ++ax) {
        const float bl = fminf(fmaxf(m3[ax] - 3.f * sg[ax], lo3[ax]), hi3[ax]);
        const float bh = fminf(fmaxf(m3[ax] + 3.f * sg[ax], lo3[ax]), hi3[ax]);
        valid = valid &&
                (((bl > lo3[ax]) || (bh > lo3[ax])) && ((bl < hi3[ax]) || (bh < hi3[ax])));
        const int a = (int)((bl - lo3[ax]) / VOX);
        const int b = (int)((bh - lo3[ax]) / VOX);
        int s = b - a + 1;
        s = min(s, KMAX);             // reference's static K tile
        s = min(s, dims[ax] - a);     // vox < dims mask
        s = max(s, 0);
        il[ax] = a;
        sp[ax] = s;
    }

    const bool live = valid && sp[0] > 0 && sp[1] > 0 && sp[2] > 0;
    const int pack = live ? (sp[0] | (sp[1] << 8) | (sp[2] << 16)) : 0;

    float4* R4 = (float4*)(recs + (size_t)g * REC_DW);
    const float* F = feats + (size_t)g * NF;
    R4[0] = make_float4(mx, my, mz, opac[g]);
    R4[1] = make_float4(NHL2E * a00, NHL2E * a11, NHL2E * a22, 2.f * NHL2E * a01);
    R4[2] = make_float4(2.f * NHL2E * a02, 2.f * NHL2E * a12, F[0], F[1]);
    R4[3] = make_float4(F[2], F[3], F[4], F[5]);
    R4[4] = make_float4(F[6], F[7], F[8], F[9]);
    R4[5] = make_float4(F[10], F[11], F[12], F[13]);
    R4[6] = make_float4(F[14], F[15], F[16], __int_as_float(il[0]));
    R4[7] = make_float4(__int_as_float(il[1]), __int_as_float(il[2]),
                        __int_as_float(pack), 0.f);

    if (!live) return;

    // scatter into overlapped tiles (<= 4x4 tiles since bbox span <= 10 voxels)
    const int tx0 = il[0] / TILE_XY;
    const int tx1 = (il[0] + sp[0] - 1) / TILE_XY;
    const int ty0 = il[1] / TILE_XY;
    const int ty1 = (il[1] + sp[1] - 1) / TILE_XY;
    for (int tx = tx0; tx <= tx1; ++tx)
        for (int ty = ty0; ty <= ty1; ++ty) {
            const int tile = tx * NTY + ty;
            const int idx = atomicAdd(counts + tile, 1);
            if (idx < CAP) lists[(size_t)tile * CAP + idx] = g;
        }
}

// ---------------------------------------------------------------------------
// Kernel B: ONE WAVE per 4x4x16 tile; each lane owns 4 voxels along z.
// The wave stages a chunk of up to 32 records (128 B each) from global to LDS
// in ONE parallel round (2 lanes/entry x 4 dwordx4), then the entry loop reads
// broadcast float4s from LDS — no per-entry global-latency chain.
// ---------------------------------------------------------------------------
__global__ __launch_bounds__(64) void gv_gather(
    const float* __restrict__ recs,
    const int* __restrict__ counts,
    const int* __restrict__ lists,
    const float* __restrict__ empty_scalar,
    float* __restrict__ out)           // [NV] density, then [NV,18] feats
{
    __shared__ float4 s_rec[2][CH * REC_V4];   // 2 x 32 x 128 B = 8 KB

    const int tile = blockIdx.x;
    const int tx = tile / NTY;
    const int ty = tile - tx * NTY;

    const int lane = threadIdx.x;      // 0..63
    const int lx = lane >> 4;
    const int ly = (lane >> 2) & 3;
    const int vz0 = (lane & 3) << 2;   // z-group base: 0,4,8,12

    const int vx = tx * TILE_XY + lx;
    const int vy = ty * TILE_XY + ly;
    const float cx = ((float)vx + 0.5f) * VOX + LO0;
    const float cy = ((float)vy + 0.5f) * VOX + LO1;

    const int n = min(counts[tile], CAP);
    const int* __restrict__ lst = lists + (size_t)tile * CAP;

    float accd[4] = { 0.f, 0.f, 0.f, 0.f };
    float accf[4][NF];
#pragma unroll
    for (int j = 0; j < 4; ++j)
#pragma unroll
        for (int c = 0; c < NF; ++c) accf[j][c] = 0.f;

    // staging lane roles: entry e_ld = lane/2, half q_ld = lane&1 (64 B each)
    const int e_ld = lane >> 1;
    const int q_ld = lane & 1;
    float4 r0, r1, r2, r3;

    const int nchunk = (n + CH - 1) / CH;
    int buf = 0;

    // preload + stage chunk 0
    if (nchunk > 0) {
        const int idx = e_ld;
        if (idx < n) {
            const float4* src = (const float4*)recs + (size_t)lst[idx] * REC_V4 + q_ld * 4;
            r0 = src[0]; r1 = src[1]; r2 = src[2]; r3 = src[3];
            float4* dst = &s_rec[0][e_ld * REC_V4 + q_ld * 4];
            dst[0] = r0; dst[1] = r1; dst[2] = r2; dst[3] = r3;
        }
    }
    __syncthreads();

    for (int c = 0; c < nchunk; ++c) {
        // issue next chunk's global loads before processing (latency overlap)
        const int nidx = (c + 1) * CH + e_ld;
        const bool nact = (c + 1 < nchunk) && (nidx < n);
        if (nact) {
            const float4* src = (const float4*)recs + (size_t)lst[nidx] * REC_V4 + q_ld * 4;
            r0 = src[0]; r1 = src[1]; r2 = src[2]; r3 = src[3];
        }

        const int m = min(CH, n - c * CH);
        for (int e = 0; e < m; ++e) {
            const float4* E = &s_rec[buf][e * REC_V4];
            const float4 e0 = E[0], e1 = E[1], e2 = E[2], e3 = E[3];
            const float4 e4 = E[4], e5 = E[5], e6 = E[6], e7 = E[7];

            const int il0 = __float_as_int(e6.w);
            const int il1 = __float_as_int(e7.x);
            const int il2 = __float_as_int(e7.y);
            const int pk  = __float_as_int(e7.z);

            const bool inxy =
                ((unsigned)(vx - il0) < (unsigned)(pk & 255)) &
                ((unsigned)(vy - il1) < (unsigned)((pk >> 8) & 255));
            const unsigned spz = (unsigned)((pk >> 16) & 255);

            const float dx = cx - e0.x;
            const float dy = cy - e0.y;
            // pre-scaled exponent: ee = -0.5*log2e*maha, dens = op * 2^ee
            const float q0 = e1.x * dx * dx + e1.y * dy * dy + e1.w * dx * dy;
            const float q1 = e2.x * dx + e2.y * dy;
            const float A22 = e1.z;
            const float op = e0.w, mzv = e0.z;

            const float f[NF] = { e2.z, e2.w, e3.x, e3.y, e3.z, e3.w,
                                  e4.x, e4.y, e4.z, e4.w,
                                  e5.x, e5.y, e5.z, e5.w,
                                  e6.x, e6.y, e6.z };

#pragma unroll
            for (int j = 0; j < 4; ++j) {
                const float cz = ((float)(vz0 + j) + 0.5f) * VOX + LO2;
                const float dz = cz - mzv;
                const float ee = q0 + dz * (q1 + A22 * dz);
                const bool in = inxy & ((unsigned)(vz0 + j - il2) < spz);
                const float dens = op * exp2f(ee);
                if (in) {
                    accd[j] += dens;
#pragma unroll
                    for (int cc = 0; cc < NF; ++cc) accf[j][cc] += dens * f[cc];
                }
            }
        }

        if (nact) {
            float4* dst = &s_rec[buf ^ 1][e_ld * REC_V4 + q_ld * 4];
            dst[0] = r0; dst[1] = r1; dst[2] = r2; dst[3] = r3;
        }
        __syncthreads();
        buf ^= 1;
    }

    // Epilogue: empty gaussian + normalize + store
    const float es = empty_scalar[0];
    const float ex = (cx - 0.5f * (LO0 + HI0)) / (HI0 - LO0);
    const float ey = (cy - 0.5f * (LO1 + HI1)) / (HI1 - LO1);
    const float exy = ex * ex + ey * ey;

    float dsv[4], dev[4];
#pragma unroll
    for (int j = 0; j < 4; ++j) {
        const float cz = ((float)(vz0 + j) + 0.5f) * VOX + LO2;
        const float ez = (cz - 0.5f * (LO2 + HI2)) / (HI2 - LO2);
        dev[j] = __expf(-0.5f * (exy + ez * ez));
        dsv[j] = accd[j] + dev[j];
    }

    const int vbase = (vx * GW + vy) * GD + vz0;     // multiple of 4
    *(float4*)(out + vbase) = make_float4(dsv[0], dsv[1], dsv[2], dsv[3]);

#pragma unroll
    for (int j = 0; j < 4; ++j) {
        const float inv = 1.f / fmaxf(dsv[j], EPSV);
        float vals[NCLS];
#pragma unroll
        for (int c = 0; c < NF; ++c) vals[c] = accf[j][c] * inv;
        vals[NF] = dev[j] * es * inv;
        float2* of2 = (float2*)(out + NV + (size_t)(vbase + j) * NCLS);  // 8B aligned
#pragma unroll
        for (int p = 0; p < NCLS / 2; ++p)
            of2[p] = make_float2(vals[2 * p], vals[2 * p + 1]);
    }
}

extern "C" void kernel_launch(void* const* d_in, const int* in_sizes, int n_in,
                              void* d_out, int out_size, void* d_ws, size_t ws_size,
                              hipStream_t stream) {
    const float* means  = (const float*)d_in[0];
    const float* opac   = (const float*)d_in[1];
    const float* feats  = (const float*)d_in[2];
    const float* scales = (const float*)d_in[3];
    const float* rots   = (const float*)d_in[4];
    const float* esc    = (const float*)d_in[5];

    // workspace layout (16B-aligned): recs | counts | lists
    float* recs   = (float*)d_ws;                             // 1 MB
    int*   counts = (int*)(recs + (size_t)NG * REC_DW);       // 10 KB
    int*   lists  = counts + ((NT + 63) & ~63);               // 10.2 MB

    hipMemsetAsync(counts, 0, sizeof(int) * ((NT + 63) & ~63), stream);

    gv_bin<<<NG / 256, 256, 0, stream>>>(means, opac, feats, scales, rots,
                                         recs, counts, lists);
    gv_gather<<<NT, 64, 0, stream>>>(recs, counts, lists, esc, (float*)d_out);
}

// Round 7
// 104.983 us; speedup vs baseline: 13.3931x; 1.0038x over previous
//
#include <hip/hip_runtime.h>

// Problem constants (match reference)
namespace {
constexpr int GH = 200, GW = 200, GD = 16;
constexpr int NV = GH * GW * GD;        // 640000 voxels
constexpr int NCLS = 18;                // output feature channels
constexpr int NF = 17;                  // per-gaussian feature channels (class 17 is zero)
constexpr int NG = 8192;
constexpr int KMAX = 10;                // static tile bound from reference
constexpr float VOX = 0.4f;
constexpr float LO0 = -40.f, LO1 = -40.f, LO2 = -1.f;
constexpr float HI0 = 40.f, HI1 = 40.f, HI2 = 5.4f;
constexpr float EPSV = 1e-6f;

constexpr int TILE_XY = 4;              // tile = 4x4x16 voxels, one wave per tile
constexpr int NTX = GH / TILE_XY;       // 50
constexpr int NTY = GW / TILE_XY;       // 50
constexpr int NT = NTX * NTY;           // 2500 tiles
constexpr int REC_DW = 32;              // record: 32 dwords = 128 B (incl. box)
constexpr int REC_V4 = REC_DW / 4;      // 8 float4
constexpr int CAP = 128;                // per-tile capacity (avg ~17, >25 sigma)
constexpr int CH = 32;                  // entries staged per LDS chunk

constexpr float NHL2E = -0.72134752044448170368f;  // -0.5 * log2(e)
}

// ---------------------------------------------------------------------------
// Kernel A: one thread per gaussian. Bbox math is bit-identical to the
// reference (literal /0.4f, truncating casts, clip=min(max)). The full 128 B
// evaluation record is written INLINE into every overlapped tile's list —
// gather needs no indirection and stages contiguous memory.
// Record (floats): [0..2]=mean, [3]=opacity,
// [4]=s*a00 [5]=s*a11 [6]=s*a22 [7]=2s*a01 [8]=2s*a02 [9]=2s*a12 (s=-0.5*log2e)
// [10..26]=feats, [27..29]=il (int bits), [30]=sp pack (int bits), [31]=0
// ---------------------------------------------------------------------------
__global__ __launch_bounds__(64) void gv_bin(
    const float* __restrict__ means,   // [NG,3]
    const float* __restrict__ opac,    // [NG,1]
    const float* __restrict__ feats,   // [NG,17]
    const float* __restrict__ scales,  // [NG,3]
    const float* __restrict__ rots,    // [NG,4] wxyz
    int* __restrict__ counts,          // [NT], pre-zeroed
    float4* __restrict__ lists)        // [NT * CAP * REC_V4]
{
    const int g = blockIdx.x * blockDim.x + threadIdx.x;
    if (g >= NG) return;

    const float mx = means[g * 3 + 0];
    const float my = means[g * 3 + 1];
    const float mz = means[g * 3 + 2];
    const float sx = scales[g * 3 + 0];
    const float sy = scales[g * 3 + 1];
    const float sz = scales[g * 3 + 2];
    float qw = rots[g * 4 + 0];
    float qx = rots[g * 4 + 1];
    float qy = rots[g * 4 + 2];
    float qz = rots[g * 4 + 3];

    // normalized quaternion -> rotation matrix
    const float qn = rsqrtf(qw * qw + qx * qx + qy * qy + qz * qz);
    qw *= qn; qx *= qn; qy *= qn; qz *= qn;
    const float r00 = 1.f - 2.f * (qy * qy + qz * qz);
    const float r01 = 2.f * (qx * qy - qw * qz);
    const float r02 = 2.f * (qx * qz + qw * qy);
    const float r10 = 2.f * (qx * qy + qw * qz);
    const float r11 = 1.f - 2.f * (qx * qx + qz * qz);
    const float r12 = 2.f * (qy * qz - qw * qx);
    const float r20 = 2.f * (qx * qz - qw * qy);
    const float r21 = 2.f * (qy * qz + qw * qx);
    const float r22 = 1.f - 2.f * (qx * qx + qy * qy);

    const float s0 = sx * sx, s1 = sy * sy, s2 = sz * sz;
    const float c00 = r00 * r00 * s0 + r01 * r01 * s1 + r02 * r02 * s2;
    const float c11 = r10 * r10 * s0 + r11 * r11 * s1 + r12 * r12 * s2;
    const float c22 = r20 * r20 * s0 + r21 * r21 * s1 + r22 * r22 * s2;
    const float i0 = 1.f / s0, i1 = 1.f / s1, i2 = 1.f / s2;
    const float a00 = r00 * r00 * i0 + r01 * r01 * i1 + r02 * r02 * i2;
    const float a01 = r00 * r10 * i0 + r01 * r11 * i1 + r02 * r12 * i2;
    const float a02 = r00 * r20 * i0 + r01 * r21 * i1 + r02 * r22 * i2;
    const float a11 = r10 * r10 * i0 + r11 * r11 * i1 + r12 * r12 * i2;
    const float a12 = r10 * r20 * i0 + r11 * r21 * i1 + r12 * r22 * i2;
    const float a22 = r20 * r20 * i0 + r21 * r21 * i1 + r22 * r22 * i2;

    const float m3[3] = { mx, my, mz };
    const float sg[3] = { sqrtf(c00), sqrtf(c11), sqrtf(c22) };
    const float lo3[3] = { LO0, LO1, LO2 };
    const float hi3[3] = { HI0, HI1, HI2 };
    const int dims[3] = { GH, GW, GD };

    int il[3], sp[3];
    bool valid = true;
#pragma unroll
    for (int ax = 0; ax < 3; ++ax) {
        const float bl = fminf(fmaxf(m3[ax] - 3.f * sg[ax], lo3[ax]), hi3[ax]);
        const float bh = fminf(fmaxf(m3[ax] + 3.f * sg[ax], lo3[ax]), hi3[ax]);
        valid = valid &&
                (((bl > lo3[ax]) || (bh > lo3[ax])) && ((bl < hi3[ax]) || (bh < hi3[ax])));
        const int a = (int)((bl - lo3[ax]) / VOX);
        const int b = (int)((bh - lo3[ax]) / VOX);
        int s = b - a + 1;
        s = min(s, KMAX);             // reference's static K tile
        s = min(s, dims[ax] - a);     // vox < dims mask
        s = max(s, 0);
        il[ax] = a;
        sp[ax] = s;
    }

    if (!valid || sp[0] <= 0 || sp[1] <= 0 || sp[2] <= 0) return;
    const int pack = sp[0] | (sp[1] << 8) | (sp[2] << 16);

    const float* F = feats + (size_t)g * NF;
    float4 R[REC_V4];
    R[0] = make_float4(mx, my, mz, opac[g]);
    R[1] = make_float4(NHL2E * a00, NHL2E * a11, NHL2E * a22, 2.f * NHL2E * a01);
    R[2] = make_float4(2.f * NHL2E * a02, 2.f * NHL2E * a12, F[0], F[1]);
    R[3] = make_float4(F[2], F[3], F[4], F[5]);
    R[4] = make_float4(F[6], F[7], F[8], F[9]);
    R[5] = make_float4(F[10], F[11], F[12], F[13]);
    R[6] = make_float4(F[14], F[15], F[16], __int_as_float(il[0]));
    R[7] = make_float4(__int_as_float(il[1]), __int_as_float(il[2]),
                       __int_as_float(pack), 0.f);

    // scatter the record into overlapped tiles (<= 4x4 tiles)
    const int tx0 = il[0] / TILE_XY;
    const int tx1 = (il[0] + sp[0] - 1) / TILE_XY;
    const int ty0 = il[1] / TILE_XY;
    const int ty1 = (il[1] + sp[1] - 1) / TILE_XY;
    for (int tx = tx0; tx <= tx1; ++tx)
        for (int ty = ty0; ty <= ty1; ++ty) {
            const int tile = tx * NTY + ty;
            const int idx = atomicAdd(counts + tile, 1);
            if (idx < CAP) {
                float4* dst = lists + ((size_t)tile * CAP + idx) * REC_V4;
#pragma unroll
                for (int u = 0; u < REC_V4; ++u) dst[u] = R[u];
            }
        }
}

// ---------------------------------------------------------------------------
// Kernel B: ONE WAVE per 4x4x16 tile; each lane owns 4 voxels along z.
// The wave stages up to 32 inline records (contiguous 8 KB!) from the tile's
// list to LDS in one coalesced round (2 lanes/entry x 4 dwordx4), then the
// entry loop reads broadcast float4s from LDS.
// ---------------------------------------------------------------------------
__global__ __launch_bounds__(64) void gv_gather(
    const int* __restrict__ counts,
    const float4* __restrict__ lists,
    const float* __restrict__ empty_scalar,
    float* __restrict__ out)           // [NV] density, then [NV,18] feats
{
    __shared__ float4 s_rec[2][CH * REC_V4];   // 2 x 32 x 128 B = 8 KB

    const int tile = blockIdx.x;
    const int tx = tile / NTY;
    const int ty = tile - tx * NTY;

    const int lane = threadIdx.x;      // 0..63
    const int lx = lane >> 4;
    const int ly = (lane >> 2) & 3;
    const int vz0 = (lane & 3) << 2;   // z-group base: 0,4,8,12

    const int vx = tx * TILE_XY + lx;
    const int vy = ty * TILE_XY + ly;
    const float cx = ((float)vx + 0.5f) * VOX + LO0;
    const float cy = ((float)vy + 0.5f) * VOX + LO1;

    const int n = min(counts[tile], CAP);
    const float4* __restrict__ tl = lists + (size_t)tile * CAP * REC_V4;

    float accd[4] = { 0.f, 0.f, 0.f, 0.f };
    float accf[4][NF];
#pragma unroll
    for (int j = 0; j < 4; ++j)
#pragma unroll
        for (int c = 0; c < NF; ++c) accf[j][c] = 0.f;

    // staging lane roles: entry e_ld = lane/2, half q_ld = lane&1 (64 B each)
    const int e_ld = lane >> 1;
    const int q_ld = lane & 1;
    float4 r0, r1, r2, r3;

    const int nchunk = (n + CH - 1) / CH;
    int buf = 0;

    if (nchunk > 0 && e_ld < n) {
        const float4* src = tl + (size_t)e_ld * REC_V4 + q_ld * 4;
        r0 = src[0]; r1 = src[1]; r2 = src[2]; r3 = src[3];
        float4* dst = &s_rec[0][e_ld * REC_V4 + q_ld * 4];
        dst[0] = r0; dst[1] = r1; dst[2] = r2; dst[3] = r3;
    }
    __syncthreads();

    for (int c = 0; c < nchunk; ++c) {
        // issue next chunk's coalesced loads before processing this one
        const int nidx = (c + 1) * CH + e_ld;
        const bool nact = (c + 1 < nchunk) && (nidx < n);
        if (nact) {
            const float4* src = tl + (size_t)nidx * REC_V4 + q_ld * 4;
            r0 = src[0]; r1 = src[1]; r2 = src[2]; r3 = src[3];
        }

        const int m = min(CH, n - c * CH);
        for (int e = 0; e < m; ++e) {
            const float4* E = &s_rec[buf][e * REC_V4];
            const float4 e0 = E[0], e1 = E[1], e2 = E[2], e3 = E[3];
            const float4 e4 = E[4], e5 = E[5], e6 = E[6], e7 = E[7];

            const int il0 = __float_as_int(e6.w);
            const int il1 = __float_as_int(e7.x);
            const int il2 = __float_as_int(e7.y);
            const int pk  = __float_as_int(e7.z);

            const bool inxy =
                ((unsigned)(vx - il0) < (unsigned)(pk & 255)) &
                ((unsigned)(vy - il1) < (unsigned)((pk >> 8) & 255));
            const unsigned spz = (unsigned)((pk >> 16) & 255);

            const float dx = cx - e0.x;
            const float dy = cy - e0.y;
            // pre-scaled exponent: ee = -0.5*log2e*maha, dens = op * 2^ee
            const float q0 = e1.x * dx * dx + e1.y * dy * dy + e1.w * dx * dy;
            const float q1 = e2.x * dx + e2.y * dy;
            const float A22 = e1.z;
            const float op = e0.w, mzv = e0.z;

            const float f[NF] = { e2.z, e2.w, e3.x, e3.y, e3.z, e3.w,
                                  e4.x, e4.y, e4.z, e4.w,
                                  e5.x, e5.y, e5.z, e5.w,
                                  e6.x, e6.y, e6.z };

#pragma unroll
            for (int j = 0; j < 4; ++j) {
                const float cz = ((float)(vz0 + j) + 0.5f) * VOX + LO2;
                const float dz = cz - mzv;
                const float ee = q0 + dz * (q1 + A22 * dz);
                const bool in = inxy & ((unsigned)(vz0 + j - il2) < spz);
                const float dens = op * __builtin_amdgcn_exp2f(ee);
                if (in) {
                    accd[j] += dens;
#pragma unroll
                    for (int cc = 0; cc < NF; ++cc) accf[j][cc] += dens * f[cc];
                }
            }
        }

        if (nact) {
            float4* dst = &s_rec[buf ^ 1][e_ld * REC_V4 + q_ld * 4];
            dst[0] = r0; dst[1] = r1; dst[2] = r2; dst[3] = r3;
        }
        __syncthreads();
        buf ^= 1;
    }

    // Epilogue: empty gaussian + normalize + store
    const float es = empty_scalar[0];
    const float ex = (cx - 0.5f * (LO0 + HI0)) / (HI0 - LO0);
    const float ey = (cy - 0.5f * (LO1 + HI1)) / (HI1 - LO1);
    const float exy = ex * ex + ey * ey;

    float dsv[4], dev[4];
#pragma unroll
    for (int j = 0; j < 4; ++j) {
        const float cz = ((float)(vz0 + j) + 0.5f) * VOX + LO2;
        const float ez = (cz - 0.5f * (LO2 + HI2)) / (HI2 - LO2);
        dev[j] = __expf(-0.5f * (exy + ez * ez));
        dsv[j] = accd[j] + dev[j];
    }

    const int vbase = (vx * GW + vy) * GD + vz0;     // multiple of 4
    *(float4*)(out + vbase) = make_float4(dsv[0], dsv[1], dsv[2], dsv[3]);

#pragma unroll
    for (int j = 0; j < 4; ++j) {
        const float inv = 1.f / fmaxf(dsv[j], EPSV);
        float vals[NCLS];
#pragma unroll
        for (int c = 0; c < NF; ++c) vals[c] = accf[j][c] * inv;
        vals[NF] = dev[j] * es * inv;
        float2* of2 = (float2*)(out + NV + (size_t)(vbase + j) * NCLS);  // 8B aligned
#pragma unroll
        for (int p = 0; p < NCLS / 2; ++p)
            of2[p] = make_float2(vals[2 * p], vals[2 * p + 1]);
    }
}

extern "C" void kernel_launch(void* const* d_in, const int* in_sizes, int n_in,
                              void* d_out, int out_size, void* d_ws, size_t ws_size,
                              hipStream_t stream) {
    const float* means  = (const float*)d_in[0];
    const float* opac   = (const float*)d_in[1];
    const float* feats  = (const float*)d_in[2];
    const float* scales = (const float*)d_in[3];
    const float* rots   = (const float*)d_in[4];
    const float* esc    = (const float*)d_in[5];

    // workspace layout (16B-aligned): counts | lists (inline records)
    int*    counts = (int*)d_ws;                              // 10 KB
    float4* lists  = (float4*)((char*)d_ws + 64 * 1024);      // 2500*128*128B = 40 MB

    hipMemsetAsync(counts, 0, sizeof(int) * NT, stream);

    gv_bin<<<NG / 64, 64, 0, stream>>>(means, opac, feats, scales, rots,
                                       counts, lists);
    gv_gather<<<NT, 64, 0, stream>>>(counts, lists, esc, (float*)d_out);
}